// Round 12
// baseline (286.527 us; speedup 1.0000x reference)
//
#include <hip/hip_runtime.h>
#include <hip/hip_bf16.h>
#include <math.h>

typedef __attribute__((ext_vector_type(8))) short bf16x8;
typedef __attribute__((ext_vector_type(4))) float f32x4;
typedef __attribute__((ext_vector_type(2))) unsigned u32x2;

#define MTOT  131072
#define HW16K 16384

__device__ inline float bf2f(unsigned short u) {
    union { unsigned u; float f; } x; x.u = ((unsigned)u) << 16; return x.f;
}
__device__ inline unsigned short f2bf(float a) {
    __hip_bfloat16 h = __float2bfloat16(a);
    union { __hip_bfloat16 h; unsigned short u; } c; c.h = h; return c.u;
}
__device__ inline unsigned pack2bf(float a, float b) {
    __hip_bfloat162 h = __float22bfloat162_rn(make_float2(a, b));
    union { __hip_bfloat162 h; unsigned u; } c; c.h = h; return c.u;
}
// tanh-form GeLU: v * sigmoid(1.5957691 v + 0.07135481 v^3).
__device__ inline float gelu(float v) {
    float u = v * fmaf(0.07135481f, v * v, 1.5957691f);
    return __fdividef(v, 1.f + __expf(-u));
}
__device__ inline void load16(const unsigned short* p, float* f) {
    uint4 u0 = *(const uint4*)p;
    uint4 u1 = *(const uint4*)(p + 8);
    unsigned w[8] = {u0.x, u0.y, u0.z, u0.w, u1.x, u1.y, u1.z, u1.w};
#pragma unroll
    for (int i = 0; i < 8; i++) {
        union { unsigned u; float f; } lo, hi;
        lo.u = w[i] << 16; hi.u = w[i] & 0xffff0000u;
        f[2 * i] = lo.f; f[2 * i + 1] = hi.f;
    }
}

// ------------------------------------------------ weights fp32 -> bf16
// All GEMM weights stored as MFMA fragment tiles [(nt*KF+kf)*16+row][32]:
// a 64-lane fragment load is one dense 1KB region.
// qkv rows permuted (planar output); proj/fc2 rows slot-permuted so
// D-fragments align with fc1 B-frags / in-register residual.
__global__ __launch_bounds__(256) void k_prep(const float* __restrict__ qw,
                                              const float* __restrict__ pw,
                                              const float* __restrict__ f1,
                                              const float* __restrict__ f2,
                                              const float* __restrict__ pb,
                                              const float* __restrict__ l2w,
                                              const float* __restrict__ l2b,
                                              const float* __restrict__ f2b,
                                              unsigned short* __restrict__ wqt,
                                              unsigned short* __restrict__ wpt,
                                              unsigned short* __restrict__ w1t,
                                              unsigned short* __restrict__ w2t,
                                              float* __restrict__ scal) {
    int t = blockIdx.x * 256 + threadIdx.x;
    if (t < 27648) {
        int row = t / 96, col = t - row * 96;
        int s = row / 96;            // 0=q 1=k 2=v
        int rem = row - s * 96;
        int di = rem >> 5;
        int hd = (rem >> 4) & 1;
        int c  = rem & 15;
        int nrow = s * 96 + (di * 2 + hd) * 16 + c;   // plane (s*6+g), chan c
        wqt[(((nrow >> 4) * 3 + (col >> 5)) * 16 + (nrow & 15)) * 32 + (col & 31)]
            = f2bf(qw[t]);
    }
    else if (t < 36864) {   // proj -> fragment tiles, slot-permuted rows
        int t2 = t - 27648;
        int och = t2 / 96, ich = t2 - och * 96;
        int nt = ((och >> 5) << 1) + ((och >> 2) & 1);
        int j  = ((och >> 3) & 3) * 4 + (och & 3);
        wpt[((nt * 3 + (ich >> 5)) * 16 + j) * 32 + (ich & 31)] = f2bf(pw[t2]);
    }
    else if (t < 73728) {   // fc1 -> fragment tiles, rows permuted so D==fc2 B-frag
        int t2 = t - 36864;
        int och = t2 / 96, col = t2 - och * 96;       // och1 0..383, k 0..95
        int f  = och >> 5;
        int p  = och & 31;
        int q  = p >> 3, tt = (p >> 2) & 1, r = p & 3;
        int tile = f * 2 + tt;
        int j = q * 4 + r;
        w1t[((tile * 3 + (col >> 5)) * 16 + j) * 32 + (col & 31)] = f2bf(f1[t2]);
    }
    else if (t < 110592) {  // fc2 -> fragment tiles, slot-permuted rows
        int t3 = t - 73728;
        int och = t3 / 384, ich = t3 - och * 384;
        int nt = ((och >> 5) << 1) + ((och >> 2) & 1);
        int j  = ((och >> 3) & 3) * 4 + (och & 3);
        w2t[((nt * 12 + (ich >> 5)) * 16 + j) * 32 + (ich & 31)] = f2bf(f2[t3]);
    }
    else if (t < 110976) {  // slot-ordered scalar vectors: pb, ln2w, ln2b, fc2b
        int i = t - 110592;
        int s = i / 96, slot = i - s * 96;
        int nt = slot >> 4, qq = (slot >> 2) & 3, r = slot & 3;
        int c = ((nt >> 1) << 5) + qq * 8 + ((nt & 1) << 2) + r;
        const float* src = (s == 0) ? pb : (s == 1) ? l2w : (s == 2) ? l2b : f2b;
        scal[i] = src[c];
    }
}

// ------------------------------------------------ fused LN1 + qkv GEMM (v4)
// 1024 threads, 512 px/block, grid 256 (exactly 1 block/CU).
// LN stats pairing is INTRA-wave: wave owns 32 px, lane = (half=lane>>5,
// px=lane&31); reduction = one __shfl_xor(s,32). No ps/ps2 LDS, no stats
// barrier. LDS = bufbf 100KB + Bs 54KB = 157.7KB -> 16 waves/CU = 4/SIMD
// (2x the old 512-thread version, which was the pipeline's occupancy floor).
__global__ __launch_bounds__(1024) void k_ln1qkv(const float* __restrict__ x,
                                                 const float* __restrict__ w,
                                                 const float* __restrict__ bln,
                                                 const unsigned short* __restrict__ wqt,
                                                 unsigned short* __restrict__ qkvb) {
    __shared__ unsigned short bufbf[512 * 100];   // 102400 B
    __shared__ unsigned short Bs[288 * 96];       // 55296 B, frag-tile layout
    int tid = threadIdx.x;
    int gp0 = blockIdx.x * 512;
    int b = gp0 >> 14, pix0 = gp0 & 16383;
    int lane = tid & 63, wv = tid >> 6;
    int half = lane >> 5;                 // 0/1: channel half
    int p = wv * 32 + (lane & 31);        // block-local pixel 0..511

    for (int i = tid; i < 3456; i += 1024)
        ((uint4*)Bs)[i] = ((const uint4*)wqt)[i];

    float val[48];
    float s = 0.f, s2 = 0.f;
#pragma unroll
    for (int i = 0; i < 48; i++) {
        int c = half * 48 + i;
        float v = x[((size_t)b * 96 + c) * HW16K + pix0 + p];
        val[i] = v; s += v; s2 += v * v;
    }
    s += __shfl_xor(s, 32);
    s2 += __shfl_xor(s2, 32);
    float mu = s * (1.f / 96.f);
    float inv = rsqrtf(s2 * (1.f / 96.f) - mu * mu + 1e-5f);
#pragma unroll
    for (int i = 0; i < 24; i++) {
        int c = half * 48 + 2 * i;
        float n0 = (val[2 * i] - mu) * inv * w[c] + bln[c];
        float n1 = (val[2 * i + 1] - mu) * inv * w[c + 1] + bln[c + 1];
        *(unsigned*)(bufbf + p * 100 + c) = pack2bf(n0, n1);
    }
    __syncthreads();

    int q = lane >> 4, l15 = lane & 15;
#pragma unroll 1
    for (int it = 0; it < 2; it++) {
        int pxl = (wv * 2 + it) * 16 + l15;   // 0..511
        bf16x8 pf[3];
#pragma unroll
        for (int f = 0; f < 3; f++)
            pf[f] = *(const bf16x8*)(bufbf + pxl * 100 + q * 8 + f * 32);
        int gpx = gp0 + pxl;
#pragma unroll
        for (int nt = 0; nt < 18; nt++) {
            f32x4 acc = (f32x4){0.f, 0.f, 0.f, 0.f};
#pragma unroll
            for (int kf = 0; kf < 3; kf++) {
                bf16x8 wf = *(const bf16x8*)(Bs + ((nt * 3 + kf) * 16 + l15) * 32 + q * 8);
                acc = __builtin_amdgcn_mfma_f32_16x16x32_bf16(wf, pf[kf], acc, 0, 0, 0);
            }
            u32x2 pk = { pack2bf(acc[0], acc[1]), pack2bf(acc[2], acc[3]) };
            __builtin_nontemporal_store(pk,
                (u32x2*)(qkvb + ((size_t)nt * MTOT + gpx) * 16 + q * 4));
        }
    }
}

// ------------------------------------------------ dilated attention, planar qkv
__global__ __launch_bounds__(256) void k_attn(const unsigned short* __restrict__ qkvb,
                                              unsigned short* __restrict__ attnb) {
    int bid = blockIdx.x;
    int xcd = bid & 7;
    int idx = bid >> 3;                  // 0..383
    int g   = idx >> 6;                  // 0..5
    int yb  = (xcd << 6) | (idx & 63);   // 0..511
    int px  = yb * 256 + threadIdx.x;

    int d = (g >> 1) + 1;
    int pix = px & 16383;
    int hh = pix >> 7, ww = pix & 127;
    int ibase = px & ~16383;

    const unsigned short* qpl = qkvb + (size_t)g * (MTOT * 16);
    const unsigned short* kpl = qkvb + (size_t)(6 + g) * (MTOT * 16);
    const unsigned short* vpl = qkvb + (size_t)(12 + g) * (MTOT * 16);

    float q[16];
    load16(qpl + (size_t)px * 16, q);

    float sc[9]; int nloc[9]; bool ok[9];
#pragma unroll
    for (int i = 0; i < 3; i++) {
#pragma unroll
        for (int j = 0; j < 3; j++) {
            int k9 = i * 3 + j;
            int yy = hh + (i - 1) * d;
            int xx = ww + (j - 1) * d;
            bool o_ = ((unsigned)yy < 128u) && ((unsigned)xx < 128u);
            ok[k9] = o_;
            nloc[k9] = ibase + yy * 128 + xx;
            float s = 0.f;
            if (o_) {
                float kf[16];
                load16(kpl + (size_t)nloc[k9] * 16, kf);
#pragma unroll
                for (int c = 0; c < 16; c++) s += q[c] * kf[c];
            }
            sc[k9] = s * 0.25f;
        }
    }
    float mx = sc[0];
#pragma unroll
    for (int k9 = 1; k9 < 9; k9++) mx = fmaxf(mx, sc[k9]);
    float sum = 0.f;
#pragma unroll
    for (int k9 = 0; k9 < 9; k9++) { sc[k9] = __expf(sc[k9] - mx); sum += sc[k9]; }
    float rs = 1.f / sum;

    float o[16];
#pragma unroll
    for (int c = 0; c < 16; c++) o[c] = 0.f;
#pragma unroll
    for (int k9 = 0; k9 < 9; k9++) {
        if (ok[k9]) {
            float vf[16];
            load16(vpl + (size_t)nloc[k9] * 16, vf);
            float w9 = sc[k9];
#pragma unroll
            for (int c = 0; c < 16; c++) o[c] += w9 * vf[c];
        }
    }
    uint4* orow = (uint4*)(attnb + ((size_t)g * MTOT + px) * 16);
    uint4 pk0;
    pk0.x = pack2bf(o[0] * rs, o[1] * rs);
    pk0.y = pack2bf(o[2] * rs, o[3] * rs);
    pk0.z = pack2bf(o[4] * rs, o[5] * rs);
    pk0.w = pack2bf(o[6] * rs, o[7] * rs);
    orow[0] = pk0;
    uint4 pk1;
    pk1.x = pack2bf(o[8] * rs, o[9] * rs);
    pk1.y = pack2bf(o[10] * rs, o[11] * rs);
    pk1.z = pack2bf(o[12] * rs, o[13] * rs);
    pk1.w = pack2bf(o[14] * rs, o[15] * rs);
    orow[1] = pk1;
}

// ------------------------------------------------ fused proj + res + LN2 + MLP + res
// EXACT R9 structure (measured best: 95us, VGPR 128, no spills). R10's C-fold
// (+4 VGPR -> 3 waves/SIMD, -9%) and R11's reg-cap (spills, 2x hbm_bytes)
// both regressed — do not reapply without per-kernel evidence.
__global__ __launch_bounds__(256) void k_pmlp(const unsigned short* __restrict__ attnb,
                                              const unsigned short* __restrict__ wpt,
                                              const float* __restrict__ scal,
                                              const float* __restrict__ x,
                                              const unsigned short* __restrict__ w1t,
                                              const float* __restrict__ b1,
                                              const unsigned short* __restrict__ w2t,
                                              float* __restrict__ out) {
    int tid = threadIdx.x;
    int lane = tid & 63, wv = tid >> 6;
    int q = lane >> 4, l15 = lane & 15;
    int pt0 = (blockIdx.x * 4 + wv) * 2;
    int px0 = pt0 * 16 + l15;
    int px1 = px0 + 16;

    float v0[24], v1[24];
    bf16x8 a0[3], a1[3];

#define PROJ_TILE(PX, V, A)                                                      \
    do {                                                                         \
        bf16x8 pf[3];                                                            \
        _Pragma("unroll")                                                        \
        for (int f = 0; f < 3; f++) {                                            \
            int pa = 2 * f + (q >> 1);                                           \
            pf[f] = *(const bf16x8*)(attnb + ((size_t)pa * MTOT + (PX)) * 16 + (q & 1) * 8); \
        }                                                                        \
        f32x4 acc[6];                                                            \
        _Pragma("unroll")                                                        \
        for (int nt = 0; nt < 6; nt++) acc[nt] = (f32x4){0.f, 0.f, 0.f, 0.f};    \
        _Pragma("unroll")                                                        \
        for (int nt = 0; nt < 6; nt++) {                                         \
            _Pragma("unroll")                                                    \
            for (int kf = 0; kf < 3; kf++) {                                     \
                bf16x8 wf = *(const bf16x8*)(wpt + ((nt * 3 + kf) * 16 + l15) * 32 + q * 8); \
                acc[nt] = __builtin_amdgcn_mfma_f32_16x16x32_bf16(wf, pf[kf], acc[nt], 0, 0, 0); \
            }                                                                    \
        }                                                                        \
        int bb_ = (PX) >> 14, pix_ = (PX) & 16383;                               \
        float s_ = 0.f, s2_ = 0.f;                                               \
        _Pragma("unroll")                                                        \
        for (int nt = 0; nt < 6; nt++) {                                         \
            float4 pbq = ((const float4*)scal)[nt * 4 + q];                      \
            int cb = ((nt >> 1) << 5) + q * 8 + ((nt & 1) << 2);                 \
            _Pragma("unroll")                                                    \
            for (int r = 0; r < 4; r++) {                                        \
                float xv = x[((size_t)bb_ * 96 + cb + r) * HW16K + pix_];        \
                float t_ = acc[nt][r] + ((&pbq.x)[r]) + xv;                      \
                V[nt * 4 + r] = t_; s_ += t_; s2_ += t_ * t_;                    \
            }                                                                    \
        }                                                                        \
        s_ += __shfl_xor(s_, 16);  s_ += __shfl_xor(s_, 32);                     \
        s2_ += __shfl_xor(s2_, 16); s2_ += __shfl_xor(s2_, 32);                  \
        float mu_ = s_ * (1.f / 96.f);                                           \
        float inv_ = rsqrtf(s2_ * (1.f / 96.f) - mu_ * mu_ + 1e-5f);             \
        float nrm[24];                                                           \
        _Pragma("unroll")                                                        \
        for (int nt = 0; nt < 6; nt++) {                                         \
            float4 lwq = ((const float4*)(scal + 96))[nt * 4 + q];               \
            float4 lbq = ((const float4*)(scal + 192))[nt * 4 + q];              \
            _Pragma("unroll")                                                    \
            for (int r = 0; r < 4; r++)                                          \
                nrm[nt * 4 + r] = (V[nt * 4 + r] - mu_) * inv_ * ((&lwq.x)[r]) + ((&lbq.x)[r]); \
        }                                                                        \
        _Pragma("unroll")                                                        \
        for (int kf = 0; kf < 3; kf++) {                                         \
            union { unsigned u[4]; bf16x8 v; } Hh;                               \
            Hh.u[0] = pack2bf(nrm[(kf * 2) * 4 + 0], nrm[(kf * 2) * 4 + 1]);     \
            Hh.u[1] = pack2bf(nrm[(kf * 2) * 4 + 2], nrm[(kf * 2) * 4 + 3]);     \
            Hh.u[2] = pack2bf(nrm[(kf * 2 + 1) * 4 + 0], nrm[(kf * 2 + 1) * 4 + 1]); \
            Hh.u[3] = pack2bf(nrm[(kf * 2 + 1) * 4 + 2], nrm[(kf * 2 + 1) * 4 + 3]); \
            A[kf] = Hh.v;                                                        \
        }                                                                        \
    } while (0)

    PROJ_TILE(px0, v0, a0);
    PROJ_TILE(px1, v1, a1);
#undef PROJ_TILE

    // ---- MLP ----
    f32x4 acc2a[6], acc2b[6];
#pragma unroll
    for (int nt = 0; nt < 6; nt++) {
        acc2a[nt] = (f32x4){0.f, 0.f, 0.f, 0.f};
        acc2b[nt] = (f32x4){0.f, 0.f, 0.f, 0.f};
    }

#pragma unroll 1
    for (int f = 0; f < 12; f++) {
        bf16x8 wf0[3], wf1[3];
#pragma unroll
        for (int kf = 0; kf < 3; kf++) {
            wf0[kf] = *(const bf16x8*)(w1t + (((2 * f) * 3 + kf) * 16 + l15) * 32 + q * 8);
            wf1[kf] = *(const bf16x8*)(w1t + (((2 * f + 1) * 3 + kf) * 16 + l15) * 32 + q * 8);
        }
        f32x4 c00 = (f32x4){0.f,0.f,0.f,0.f}, c01 = (f32x4){0.f,0.f,0.f,0.f};
        f32x4 c10 = (f32x4){0.f,0.f,0.f,0.f}, c11 = (f32x4){0.f,0.f,0.f,0.f};
#pragma unroll
        for (int kf = 0; kf < 3; kf++) {
            c00 = __builtin_amdgcn_mfma_f32_16x16x32_bf16(wf0[kf], a0[kf], c00, 0, 0, 0);
            c01 = __builtin_amdgcn_mfma_f32_16x16x32_bf16(wf1[kf], a0[kf], c01, 0, 0, 0);
            c10 = __builtin_amdgcn_mfma_f32_16x16x32_bf16(wf0[kf], a1[kf], c10, 0, 0, 0);
            c11 = __builtin_amdgcn_mfma_f32_16x16x32_bf16(wf1[kf], a1[kf], c11, 0, 0, 0);
        }
        bf16x8 w2f[6];
#pragma unroll
        for (int nt = 0; nt < 6; nt++)
            w2f[nt] = *(const bf16x8*)(w2t + ((nt * 12 + f) * 16 + l15) * 32 + q * 8);

        float4 bb0 = ((const float4*)b1)[8 * f + 2 * q];
        float4 bb1 = ((const float4*)b1)[8 * f + 2 * q + 1];
        union { unsigned u[4]; bf16x8 v; } H0, H1;
        H0.u[0] = pack2bf(gelu(c00[0] + bb0.x), gelu(c00[1] + bb0.y));
        H0.u[1] = pack2bf(gelu(c00[2] + bb0.z), gelu(c00[3] + bb0.w));
        H0.u[2] = pack2bf(gelu(c01[0] + bb1.x), gelu(c01[1] + bb1.y));
        H0.u[3] = pack2bf(gelu(c01[2] + bb1.z), gelu(c01[3] + bb1.w));
        H1.u[0] = pack2bf(gelu(c10[0] + bb0.x), gelu(c10[1] + bb0.y));
        H1.u[1] = pack2bf(gelu(c10[2] + bb0.z), gelu(c10[3] + bb0.w));
        H1.u[2] = pack2bf(gelu(c11[0] + bb1.x), gelu(c11[1] + bb1.y));
        H1.u[3] = pack2bf(gelu(c11[2] + bb1.z), gelu(c11[3] + bb1.w));

#pragma unroll
        for (int nt = 0; nt < 6; nt++) {
            acc2a[nt] = __builtin_amdgcn_mfma_f32_16x16x32_bf16(w2f[nt], H0.v, acc2a[nt], 0, 0, 0);
            acc2b[nt] = __builtin_amdgcn_mfma_f32_16x16x32_bf16(w2f[nt], H1.v, acc2b[nt], 0, 0, 0);
        }
    }

    // ---- epilogue: out = x1 + b2 + fc2out ----
    int b0 = px0 >> 14, pia = px0 & 16383;
    int b1i = px1 >> 14, pib = px1 & 16383;
#pragma unroll
    for (int nt = 0; nt < 6; nt++) {
        float4 b2q = ((const float4*)(scal + 288))[nt * 4 + q];
        int cb = ((nt >> 1) << 5) + q * 8 + ((nt & 1) << 2);
#pragma unroll
        for (int r = 0; r < 4; r++) {
            float ov0 = acc2a[nt][r] + ((&b2q.x)[r]) + v0[nt * 4 + r];
            __builtin_nontemporal_store(ov0, out + ((size_t)b0 * 96 + cb + r) * HW16K + pia);
            float ov1 = acc2b[nt][r] + ((&b2q.x)[r]) + v1[nt * 4 + r];
            __builtin_nontemporal_store(ov1, out + ((size_t)b1i * 96 + cb + r) * HW16K + pib);
        }
    }
}

// ------------------------------------------------ launch
extern "C" void kernel_launch(void* const* d_in, const int* in_sizes, int n_in,
                              void* d_out, int out_size, void* d_ws, size_t ws_size,
                              hipStream_t stream) {
    const float* x      = (const float*)d_in[0];
    const float* qkv_w  = (const float*)d_in[1];
    const float* proj_w = (const float*)d_in[2];
    const float* proj_b = (const float*)d_in[3];
    const float* ln1w   = (const float*)d_in[4];
    const float* ln1b   = (const float*)d_in[5];
    const float* ln2w   = (const float*)d_in[6];
    const float* ln2b   = (const float*)d_in[7];
    const float* fc1w   = (const float*)d_in[8];
    const float* fc1b   = (const float*)d_in[9];
    const float* fc2w   = (const float*)d_in[10];
    const float* fc2b   = (const float*)d_in[11];
    float* out = (float*)d_out;

    char* ws = (char*)d_ws;
    unsigned short* wqt  = (unsigned short*)(ws);            // 55296 B (frag tiles)
    unsigned short* wpt  = (unsigned short*)(ws + 55296);    // 18432 B
    unsigned short* w1t  = (unsigned short*)(ws + 73728);    // 73728 B
    unsigned short* w2t  = (unsigned short*)(ws + 147456);   // 73728 B
    float*          scal = (float*)(ws + 221184);            // 1536 B
    unsigned short* rA   = (unsigned short*)(ws + 230400);   // attnb 25165824 B
    unsigned short* qkvb = (unsigned short*)(ws + 25396224); // 75497472 B -> ~100.9 MB

    k_prep<<<434, 256, 0, stream>>>(qkv_w, proj_w, fc1w, fc2w,
                                    proj_b, ln2w, ln2b, fc2b,
                                    wqt, wpt, w1t, w2t, scal);

    // fused LN1 + qkv GEMM -> planar qkvb (18 planes); 512 px/block
    k_ln1qkv<<<256, 1024, 0, stream>>>(x, ln1w, ln1b, wqt, qkvb);
    // attention -> attnb
    k_attn<<<3072, 256, 0, stream>>>(qkvb, rA);
    // fused proj + residual + LN2 + MLP + residual -> out (R9-exact)
    k_pmlp<<<1024, 256, 0, stream>>>(rA, wpt, scal, x, w1t, fc1b, w2t, out);
}

// Round 13
// 233.589 us; speedup vs baseline: 1.2266x; 1.2266x over previous
//
#include <hip/hip_runtime.h>
#include <hip/hip_bf16.h>
#include <math.h>

typedef __attribute__((ext_vector_type(8))) short bf16x8;
typedef __attribute__((ext_vector_type(4))) float f32x4;
typedef __attribute__((ext_vector_type(2))) unsigned u32x2;

#define MTOT  131072
#define HW16K 16384

__device__ inline float bf2f(unsigned short u) {
    union { unsigned u; float f; } x; x.u = ((unsigned)u) << 16; return x.f;
}
__device__ inline unsigned short f2bf(float a) {
    __hip_bfloat16 h = __float2bfloat16(a);
    union { __hip_bfloat16 h; unsigned short u; } c; c.h = h; return c.u;
}
__device__ inline unsigned pack2bf(float a, float b) {
    __hip_bfloat162 h = __float22bfloat162_rn(make_float2(a, b));
    union { __hip_bfloat162 h; unsigned u; } c; c.h = h; return c.u;
}
// tanh-form GeLU: v * sigmoid(1.5957691 v + 0.07135481 v^3).
__device__ inline float gelu(float v) {
    float u = v * fmaf(0.07135481f, v * v, 1.5957691f);
    return __fdividef(v, 1.f + __expf(-u));
}
__device__ inline void load16(const unsigned short* p, float* f) {
    uint4 u0 = *(const uint4*)p;
    uint4 u1 = *(const uint4*)(p + 8);
    unsigned w[8] = {u0.x, u0.y, u0.z, u0.w, u1.x, u1.y, u1.z, u1.w};
#pragma unroll
    for (int i = 0; i < 8; i++) {
        union { unsigned u; float f; } lo, hi;
        lo.u = w[i] << 16; hi.u = w[i] & 0xffff0000u;
        f[2 * i] = lo.f; f[2 * i + 1] = hi.f;
    }
}

// ------------------------------------------------ weights fp32 -> bf16
// R9-exact (measured 244.0us total). wq row-major (LDS-staged by ln1qkv);
// proj/fc2 rows slot-permuted; fc1 rows permuted so D-frag == fc2 B-frag.
__global__ __launch_bounds__(256) void k_prep(const float* __restrict__ qw,
                                              const float* __restrict__ pw,
                                              const float* __restrict__ f1,
                                              const float* __restrict__ f2,
                                              const float* __restrict__ pb,
                                              const float* __restrict__ l2w,
                                              const float* __restrict__ l2b,
                                              const float* __restrict__ f2b,
                                              unsigned short* __restrict__ wq,
                                              unsigned short* __restrict__ wpt,
                                              unsigned short* __restrict__ w1t,
                                              unsigned short* __restrict__ w2t,
                                              float* __restrict__ scal) {
    int t = blockIdx.x * 256 + threadIdx.x;
    if (t < 27648) {
        int row = t / 96, col = t - row * 96;
        int s = row / 96;            // 0=q 1=k 2=v
        int rem = row - s * 96;
        int di = rem >> 5;
        int hd = (rem >> 4) & 1;
        int c  = rem & 15;
        int nrow = s * 96 + (di * 2 + hd) * 16 + c;   // plane (s*6+g), chan c
        wq[nrow * 96 + col] = f2bf(qw[t]);
    }
    else if (t < 36864) {   // proj -> fragment tiles, slot-permuted rows
        int t2 = t - 27648;
        int och = t2 / 96, ich = t2 - och * 96;
        int nt = ((och >> 5) << 1) + ((och >> 2) & 1);
        int j  = ((och >> 3) & 3) * 4 + (och & 3);
        wpt[((nt * 3 + (ich >> 5)) * 16 + j) * 32 + (ich & 31)] = f2bf(pw[t2]);
    }
    else if (t < 73728) {   // fc1 -> fragment tiles, rows permuted so D==fc2 B-frag
        int t2 = t - 36864;
        int och = t2 / 96, col = t2 - och * 96;       // och1 0..383, k 0..95
        int f  = och >> 5;
        int p  = och & 31;
        int q  = p >> 3, tt = (p >> 2) & 1, r = p & 3;
        int tile = f * 2 + tt;
        int j = q * 4 + r;
        w1t[((tile * 3 + (col >> 5)) * 16 + j) * 32 + (col & 31)] = f2bf(f1[t2]);
    }
    else if (t < 110592) {  // fc2 -> fragment tiles, slot-permuted rows
        int t3 = t - 73728;
        int och = t3 / 384, ich = t3 - och * 384;
        int nt = ((och >> 5) << 1) + ((och >> 2) & 1);
        int j  = ((och >> 3) & 3) * 4 + (och & 3);
        w2t[((nt * 12 + (ich >> 5)) * 16 + j) * 32 + (ich & 31)] = f2bf(f2[t3]);
    }
    else if (t < 110976) {  // slot-ordered scalar vectors: pb, ln2w, ln2b, fc2b
        int i = t - 110592;
        int s = i / 96, slot = i - s * 96;
        int nt = slot >> 4, qq = (slot >> 2) & 3, r = slot & 3;
        int c = ((nt >> 1) << 5) + qq * 8 + ((nt & 1) << 2) + r;
        const float* src = (s == 0) ? pb : (s == 1) ? l2w : (s == 2) ? l2b : f2b;
        scal[i] = src[c];
    }
}

// ------------------------------------------------ fused LN1 + qkv GEMM (R9-exact)
// 512 thr, 256 px/block. LN1 into LDS bf16 [256][100]; MFMA vs LDS-staged
// wq (288x104, padded rows); planar-16 nontemporal stores of qkvb.
__global__ __launch_bounds__(512) void k_ln1qkv(const float* __restrict__ x,
                                                const float* __restrict__ w,
                                                const float* __restrict__ bln,
                                                const unsigned short* __restrict__ wq,
                                                unsigned short* __restrict__ qkvb) {
    __shared__ unsigned short bufbf[256 * 100];
    __shared__ unsigned short Bs[288 * 104];
    __shared__ float ps[512], ps2[512];
    int tid = threadIdx.x;
    int gp0 = blockIdx.x * 256;
    int b = gp0 >> 14, pix0 = gp0 & 16383;
    int p = tid & 255, half = tid >> 8;

    for (int i = tid; i < 3456; i += 512) {
        int row = i / 12, col = i - row * 12;
        *(uint4*)(Bs + row * 104 + col * 8) = ((const uint4*)wq)[i];
    }

    float val[48];
    float s = 0.f, s2 = 0.f;
#pragma unroll
    for (int i = 0; i < 48; i++) {
        int c = half * 48 + i;
        float v = x[((size_t)b * 96 + c) * HW16K + pix0 + p];
        val[i] = v; s += v; s2 += v * v;
    }
    ps[tid] = s; ps2[tid] = s2;
    __syncthreads();
    float st = ps[p] + ps[p + 256];
    float st2 = ps2[p] + ps2[p + 256];
    float mu = st * (1.f / 96.f);
    float inv = rsqrtf(st2 * (1.f / 96.f) - mu * mu + 1e-5f);
#pragma unroll
    for (int i = 0; i < 24; i++) {
        int c = half * 48 + 2 * i;
        float n0 = (val[2 * i] - mu) * inv * w[c] + bln[c];
        float n1 = (val[2 * i + 1] - mu) * inv * w[c + 1] + bln[c + 1];
        *(unsigned*)(bufbf + p * 100 + c) = pack2bf(n0, n1);
    }
    __syncthreads();

    int lane = tid & 63, wv = tid >> 6;
    int q = lane >> 4, l15 = lane & 15;
#pragma unroll 1
    for (int it = 0; it < 2; it++) {
        int pxl = (wv * 2 + it) * 16 + l15;
        bf16x8 pf[3];
#pragma unroll
        for (int f = 0; f < 3; f++)
            pf[f] = *(const bf16x8*)(bufbf + pxl * 100 + q * 8 + f * 32);
        int gpx = gp0 + pxl;
#pragma unroll
        for (int nt = 0; nt < 18; nt++) {
            f32x4 acc = (f32x4){0.f, 0.f, 0.f, 0.f};
#pragma unroll
            for (int f = 0; f < 3; f++) {
                bf16x8 wf = *(const bf16x8*)(Bs + (nt * 16 + l15) * 104 + q * 8 + f * 32);
                acc = __builtin_amdgcn_mfma_f32_16x16x32_bf16(wf, pf[f], acc, 0, 0, 0);
            }
            u32x2 pk = { pack2bf(acc[0], acc[1]), pack2bf(acc[2], acc[3]) };
            __builtin_nontemporal_store(pk,
                (u32x2*)(qkvb + ((size_t)nt * MTOT + gpx) * 16 + q * 4));
        }
    }
}

// ------------------------------------------------ dilated attention, planar qkv
__global__ __launch_bounds__(256) void k_attn(const unsigned short* __restrict__ qkvb,
                                              unsigned short* __restrict__ attnb) {
    int bid = blockIdx.x;
    int xcd = bid & 7;
    int idx = bid >> 3;                  // 0..383
    int g   = idx >> 6;                  // 0..5
    int yb  = (xcd << 6) | (idx & 63);   // 0..511
    int px  = yb * 256 + threadIdx.x;

    int d = (g >> 1) + 1;
    int pix = px & 16383;
    int hh = pix >> 7, ww = pix & 127;
    int ibase = px & ~16383;

    const unsigned short* qpl = qkvb + (size_t)g * (MTOT * 16);
    const unsigned short* kpl = qkvb + (size_t)(6 + g) * (MTOT * 16);
    const unsigned short* vpl = qkvb + (size_t)(12 + g) * (MTOT * 16);

    float q[16];
    load16(qpl + (size_t)px * 16, q);

    float sc[9]; int nloc[9]; bool ok[9];
#pragma unroll
    for (int i = 0; i < 3; i++) {
#pragma unroll
        for (int j = 0; j < 3; j++) {
            int k9 = i * 3 + j;
            int yy = hh + (i - 1) * d;
            int xx = ww + (j - 1) * d;
            bool o_ = ((unsigned)yy < 128u) && ((unsigned)xx < 128u);
            ok[k9] = o_;
            nloc[k9] = ibase + yy * 128 + xx;
            float s = 0.f;
            if (o_) {
                float kf[16];
                load16(kpl + (size_t)nloc[k9] * 16, kf);
#pragma unroll
                for (int c = 0; c < 16; c++) s += q[c] * kf[c];
            }
            sc[k9] = s * 0.25f;
        }
    }
    float mx = sc[0];
#pragma unroll
    for (int k9 = 1; k9 < 9; k9++) mx = fmaxf(mx, sc[k9]);
    float sum = 0.f;
#pragma unroll
    for (int k9 = 0; k9 < 9; k9++) { sc[k9] = __expf(sc[k9] - mx); sum += sc[k9]; }
    float rs = 1.f / sum;

    float o[16];
#pragma unroll
    for (int c = 0; c < 16; c++) o[c] = 0.f;
#pragma unroll
    for (int k9 = 0; k9 < 9; k9++) {
        if (ok[k9]) {
            float vf[16];
            load16(vpl + (size_t)nloc[k9] * 16, vf);
            float w9 = sc[k9];
#pragma unroll
            for (int c = 0; c < 16; c++) o[c] += w9 * vf[c];
        }
    }
    uint4* orow = (uint4*)(attnb + ((size_t)g * MTOT + px) * 16);
    uint4 pk0;
    pk0.x = pack2bf(o[0] * rs, o[1] * rs);
    pk0.y = pack2bf(o[2] * rs, o[3] * rs);
    pk0.z = pack2bf(o[4] * rs, o[5] * rs);
    pk0.w = pack2bf(o[6] * rs, o[7] * rs);
    orow[0] = pk0;
    uint4 pk1;
    pk1.x = pack2bf(o[8] * rs, o[9] * rs);
    pk1.y = pack2bf(o[10] * rs, o[11] * rs);
    pk1.z = pack2bf(o[12] * rs, o[13] * rs);
    pk1.w = pack2bf(o[14] * rs, o[15] * rs);
    orow[1] = pk1;
}

// ------------------------------------------------ fused proj + res + LN2 + MLP + res
// R9-EXACT (measured best: 244us total, this kernel ~95us, VGPR 128, no
// spills). R10's C-fold (+4 VGPR -> 3 waves/SIMD) and R11's (256,4) cap
// (VGPR 64 -> scratch spills, 2x hbm_bytes) both regressed. Do not touch
// this kernel's register structure without per-kernel A/B counters.
__global__ __launch_bounds__(256) void k_pmlp(const unsigned short* __restrict__ attnb,
                                              const unsigned short* __restrict__ wpt,
                                              const float* __restrict__ scal,
                                              const float* __restrict__ x,
                                              const unsigned short* __restrict__ w1t,
                                              const float* __restrict__ b1,
                                              const unsigned short* __restrict__ w2t,
                                              float* __restrict__ out) {
    int tid = threadIdx.x;
    int lane = tid & 63, wv = tid >> 6;
    int q = lane >> 4, l15 = lane & 15;
    int pt0 = (blockIdx.x * 4 + wv) * 2;
    int px0 = pt0 * 16 + l15;
    int px1 = px0 + 16;

    float v0[24], v1[24];
    bf16x8 a0[3], a1[3];

#define PROJ_TILE(PX, V, A)                                                      \
    do {                                                                         \
        bf16x8 pf[3];                                                            \
        _Pragma("unroll")                                                        \
        for (int f = 0; f < 3; f++) {                                            \
            int pa = 2 * f + (q >> 1);                                           \
            pf[f] = *(const bf16x8*)(attnb + ((size_t)pa * MTOT + (PX)) * 16 + (q & 1) * 8); \
        }                                                                        \
        f32x4 acc[6];                                                            \
        _Pragma("unroll")                                                        \
        for (int nt = 0; nt < 6; nt++) acc[nt] = (f32x4){0.f, 0.f, 0.f, 0.f};    \
        _Pragma("unroll")                                                        \
        for (int nt = 0; nt < 6; nt++) {                                         \
            _Pragma("unroll")                                                    \
            for (int kf = 0; kf < 3; kf++) {                                     \
                bf16x8 wf = *(const bf16x8*)(wpt + ((nt * 3 + kf) * 16 + l15) * 32 + q * 8); \
                acc[nt] = __builtin_amdgcn_mfma_f32_16x16x32_bf16(wf, pf[kf], acc[nt], 0, 0, 0); \
            }                                                                    \
        }                                                                        \
        int bb_ = (PX) >> 14, pix_ = (PX) & 16383;                               \
        float s_ = 0.f, s2_ = 0.f;                                               \
        _Pragma("unroll")                                                        \
        for (int nt = 0; nt < 6; nt++) {                                         \
            float4 pbq = ((const float4*)scal)[nt * 4 + q];                      \
            int cb = ((nt >> 1) << 5) + q * 8 + ((nt & 1) << 2);                 \
            _Pragma("unroll")                                                    \
            for (int r = 0; r < 4; r++) {                                        \
                float xv = x[((size_t)bb_ * 96 + cb + r) * HW16K + pix_];        \
                float t_ = acc[nt][r] + ((&pbq.x)[r]) + xv;                      \
                V[nt * 4 + r] = t_; s_ += t_; s2_ += t_ * t_;                    \
            }                                                                    \
        }                                                                        \
        s_ += __shfl_xor(s_, 16);  s_ += __shfl_xor(s_, 32);                     \
        s2_ += __shfl_xor(s2_, 16); s2_ += __shfl_xor(s2_, 32);                  \
        float mu_ = s_ * (1.f / 96.f);                                           \
        float inv_ = rsqrtf(s2_ * (1.f / 96.f) - mu_ * mu_ + 1e-5f);             \
        float nrm[24];                                                           \
        _Pragma("unroll")                                                        \
        for (int nt = 0; nt < 6; nt++) {                                         \
            float4 lwq = ((const float4*)(scal + 96))[nt * 4 + q];               \
            float4 lbq = ((const float4*)(scal + 192))[nt * 4 + q];              \
            _Pragma("unroll")                                                    \
            for (int r = 0; r < 4; r++)                                          \
                nrm[nt * 4 + r] = (V[nt * 4 + r] - mu_) * inv_ * ((&lwq.x)[r]) + ((&lbq.x)[r]); \
        }                                                                        \
        _Pragma("unroll")                                                        \
        for (int kf = 0; kf < 3; kf++) {                                         \
            union { unsigned u[4]; bf16x8 v; } Hh;                               \
            Hh.u[0] = pack2bf(nrm[(kf * 2) * 4 + 0], nrm[(kf * 2) * 4 + 1]);     \
            Hh.u[1] = pack2bf(nrm[(kf * 2) * 4 + 2], nrm[(kf * 2) * 4 + 3]);     \
            Hh.u[2] = pack2bf(nrm[(kf * 2 + 1) * 4 + 0], nrm[(kf * 2 + 1) * 4 + 1]); \
            Hh.u[3] = pack2bf(nrm[(kf * 2 + 1) * 4 + 2], nrm[(kf * 2 + 1) * 4 + 3]); \
            A[kf] = Hh.v;                                                        \
        }                                                                        \
    } while (0)

    PROJ_TILE(px0, v0, a0);
    PROJ_TILE(px1, v1, a1);
#undef PROJ_TILE

    // ---- MLP ----
    f32x4 acc2a[6], acc2b[6];
#pragma unroll
    for (int nt = 0; nt < 6; nt++) {
        acc2a[nt] = (f32x4){0.f, 0.f, 0.f, 0.f};
        acc2b[nt] = (f32x4){0.f, 0.f, 0.f, 0.f};
    }

#pragma unroll 1
    for (int f = 0; f < 12; f++) {
        bf16x8 wf0[3], wf1[3];
#pragma unroll
        for (int kf = 0; kf < 3; kf++) {
            wf0[kf] = *(const bf16x8*)(w1t + (((2 * f) * 3 + kf) * 16 + l15) * 32 + q * 8);
            wf1[kf] = *(const bf16x8*)(w1t + (((2 * f + 1) * 3 + kf) * 16 + l15) * 32 + q * 8);
        }
        f32x4 c00 = (f32x4){0.f,0.f,0.f,0.f}, c01 = (f32x4){0.f,0.f,0.f,0.f};
        f32x4 c10 = (f32x4){0.f,0.f,0.f,0.f}, c11 = (f32x4){0.f,0.f,0.f,0.f};
#pragma unroll
        for (int kf = 0; kf < 3; kf++) {
            c00 = __builtin_amdgcn_mfma_f32_16x16x32_bf16(wf0[kf], a0[kf], c00, 0, 0, 0);
            c01 = __builtin_amdgcn_mfma_f32_16x16x32_bf16(wf1[kf], a0[kf], c01, 0, 0, 0);
            c10 = __builtin_amdgcn_mfma_f32_16x16x32_bf16(wf0[kf], a1[kf], c10, 0, 0, 0);
            c11 = __builtin_amdgcn_mfma_f32_16x16x32_bf16(wf1[kf], a1[kf], c11, 0, 0, 0);
        }
        bf16x8 w2f[6];
#pragma unroll
        for (int nt = 0; nt < 6; nt++)
            w2f[nt] = *(const bf16x8*)(w2t + ((nt * 12 + f) * 16 + l15) * 32 + q * 8);

        float4 bb0 = ((const float4*)b1)[8 * f + 2 * q];
        float4 bb1 = ((const float4*)b1)[8 * f + 2 * q + 1];
        union { unsigned u[4]; bf16x8 v; } H0, H1;
        H0.u[0] = pack2bf(gelu(c00[0] + bb0.x), gelu(c00[1] + bb0.y));
        H0.u[1] = pack2bf(gelu(c00[2] + bb0.z), gelu(c00[3] + bb0.w));
        H0.u[2] = pack2bf(gelu(c01[0] + bb1.x), gelu(c01[1] + bb1.y));
        H0.u[3] = pack2bf(gelu(c01[2] + bb1.z), gelu(c01[3] + bb1.w));
        H1.u[0] = pack2bf(gelu(c10[0] + bb0.x), gelu(c10[1] + bb0.y));
        H1.u[1] = pack2bf(gelu(c10[2] + bb0.z), gelu(c10[3] + bb0.w));
        H1.u[2] = pack2bf(gelu(c11[0] + bb1.x), gelu(c11[1] + bb1.y));
        H1.u[3] = pack2bf(gelu(c11[2] + bb1.z), gelu(c11[3] + bb1.w));

#pragma unroll
        for (int nt = 0; nt < 6; nt++) {
            acc2a[nt] = __builtin_amdgcn_mfma_f32_16x16x32_bf16(w2f[nt], H0.v, acc2a[nt], 0, 0, 0);
            acc2b[nt] = __builtin_amdgcn_mfma_f32_16x16x32_bf16(w2f[nt], H1.v, acc2b[nt], 0, 0, 0);
        }
    }

    // ---- epilogue: out = x1 + b2 + fc2out ----
    int b0 = px0 >> 14, pia = px0 & 16383;
    int b1i = px1 >> 14, pib = px1 & 16383;
#pragma unroll
    for (int nt = 0; nt < 6; nt++) {
        float4 b2q = ((const float4*)(scal + 288))[nt * 4 + q];
        int cb = ((nt >> 1) << 5) + q * 8 + ((nt & 1) << 2);
#pragma unroll
        for (int r = 0; r < 4; r++) {
            float ov0 = acc2a[nt][r] + ((&b2q.x)[r]) + v0[nt * 4 + r];
            __builtin_nontemporal_store(ov0, out + ((size_t)b0 * 96 + cb + r) * HW16K + pia);
            float ov1 = acc2b[nt][r] + ((&b2q.x)[r]) + v1[nt * 4 + r];
            __builtin_nontemporal_store(ov1, out + ((size_t)b1i * 96 + cb + r) * HW16K + pib);
        }
    }
}

// ------------------------------------------------ launch
extern "C" void kernel_launch(void* const* d_in, const int* in_sizes, int n_in,
                              void* d_out, int out_size, void* d_ws, size_t ws_size,
                              hipStream_t stream) {
    const float* x      = (const float*)d_in[0];
    const float* qkv_w  = (const float*)d_in[1];
    const float* proj_w = (const float*)d_in[2];
    const float* proj_b = (const float*)d_in[3];
    const float* ln1w   = (const float*)d_in[4];
    const float* ln1b   = (const float*)d_in[5];
    const float* ln2w   = (const float*)d_in[6];
    const float* ln2b   = (const float*)d_in[7];
    const float* fc1w   = (const float*)d_in[8];
    const float* fc1b   = (const float*)d_in[9];
    const float* fc2w   = (const float*)d_in[10];
    const float* fc2b   = (const float*)d_in[11];
    float* out = (float*)d_out;

    char* ws = (char*)d_ws;
    unsigned short* wq   = (unsigned short*)(ws);            // 55296 B (row-major)
    unsigned short* wpt  = (unsigned short*)(ws + 55296);    // 18432 B (slot frag tiles)
    unsigned short* w1t  = (unsigned short*)(ws + 73728);    // 73728 B
    unsigned short* w2t  = (unsigned short*)(ws + 147456);   // 73728 B (slot frag tiles)
    float*          scal = (float*)(ws + 221184);            // 1536 B
    unsigned short* rA   = (unsigned short*)(ws + 230400);   // attnb 25165824 B
    unsigned short* qkvb = (unsigned short*)(ws + 25396224); // 75497472 B -> ~100.9 MB

    k_prep<<<434, 256, 0, stream>>>(qkv_w, proj_w, fc1w, fc2w,
                                    proj_b, ln2w, ln2b, fc2b,
                                    wq, wpt, w1t, w2t, scal);

    // fused LN1 + qkv GEMM -> planar qkvb (18 planes)
    k_ln1qkv<<<512, 512, 0, stream>>>(x, ln1w, ln1b, wq, qkvb);
    // attention -> attnb
    k_attn<<<3072, 256, 0, stream>>>(qkvb, rA);
    // fused proj + residual + LN2 + MLP + residual -> out
    k_pmlp<<<1024, 256, 0, stream>>>(rA, wpt, scal, x, w1t, fc1b, w2t, out);
}